// Round 6
// baseline (267.778 us; speedup 1.0000x reference)
//
#include <hip/hip_runtime.h>
#include <hip/hip_bf16.h>
#include <hip/hip_cooperative_groups.h>

namespace cg = cooperative_groups;

// DecorrelationGradient, KAPPA = 0.5:
//   out = 0.5 * (X^T X / N) - 0.5   (diag terms cancel exactly at k=0.5)
// X [16384, 768] fp32.
//
// R6: fuse transpose -> gemm -> reduce into ONE cooperative kernel
// (512 blocks x 512 thr = exactly 2 blocks/CU co-resident, grid.sync between
// phases). KSPLIT=24 (504 gemm jobs, 1:1 with blocks), bf16 partials
// (33 MB total traffic vs 84 MB f32), diagonal tiles stage A only.
// Fallback to non-coop 3-kernel path if cooperative launch is rejected.

#define D_DIM    768
#define K_DIM    16384
#define NPAIR    21
#define KSPLIT   24
#define NBLK     512
#define XT_BYTES   ((size_t)D_DIM * K_DIM * 2)                 // 24 MiB
#define PART_BYTES ((size_t)KSPLIT * NPAIR * 16384 * 2)        // 16.5 MiB
#define SMEM_BYTES 16896   // max(phase1 2*2112*4, phase2 2*8192, phase3 2*1032*4)

__device__ __constant__ int MI_TAB[NPAIR] = {0,0,0,0,0,0, 1,1,1,1,1, 2,2,2,2, 3,3,3, 4,4, 5};
__device__ __constant__ int NI_TAB[NPAIR] = {0,1,2,3,4,5, 1,2,3,4,5, 2,3,4,5, 3,4,5, 4,5, 5};

typedef __attribute__((ext_vector_type(8))) short short8;     // bf16 A/B frag
typedef __attribute__((ext_vector_type(4))) float floatx4;    // fp32 C/D frag

typedef __attribute__((address_space(3))) unsigned short lds_ushort;
typedef __attribute__((address_space(1))) const unsigned short g_ushort;

__device__ __forceinline__ void load_lds16(const unsigned short* g, unsigned short* l) {
  __builtin_amdgcn_global_load_lds((g_ushort*)g, (lds_ushort*)l, 16, 0, 0);
}

__device__ __forceinline__ unsigned int f2bf_u(float f) {     // RNE, as uint
  unsigned int u = __float_as_uint(f);
  u += 0x7fffu + ((u >> 16) & 1u);
  return u >> 16;
}

// ---------------- phase 1: transpose + cast --------------------------------
// 3072 tiles of 64n x 64d; 1024 half-block units x exactly 3 tiles.
__device__ void phase1(const float* __restrict__ x, unsigned short* __restrict__ xt,
                       unsigned char* smem, int bid, int t) {
  const int h  = t >> 8;
  const int tt = t & 255;
  unsigned int* tileT = (unsigned int*)smem + h * 2112;   // [64][33]
  const int f4 = tt & 15;
  const int np = tt >> 4;
  const int ch = tt & 7;
  const int dr = tt >> 3;
  const int u  = bid * 2 + h;
  for (int iter = 0; iter < 3; ++iter) {
    const int tile = u + iter * 1024;
    const int dt = tile % 12;
    const int nt = tile / 12;
    const int d0 = dt * 64, n0 = nt * 64;
    __syncthreads();   // protect LDS from previous iteration's readers
#pragma unroll
    for (int j = 0; j < 2; ++j) {
      const int npg = np + 16 * j;
      const float* p0 = x + (size_t)(n0 + 2 * npg) * D_DIM + d0 + 4 * f4;
      float4 v0 = *(const float4*)p0;
      float4 v1 = *(const float4*)(p0 + D_DIM);
      tileT[(4 * f4 + 0) * 33 + npg] = f2bf_u(v0.x) | (f2bf_u(v1.x) << 16);
      tileT[(4 * f4 + 1) * 33 + npg] = f2bf_u(v0.y) | (f2bf_u(v1.y) << 16);
      tileT[(4 * f4 + 2) * 33 + npg] = f2bf_u(v0.z) | (f2bf_u(v1.z) << 16);
      tileT[(4 * f4 + 3) * 33 + npg] = f2bf_u(v0.w) | (f2bf_u(v1.w) << 16);
    }
    __syncthreads();
#pragma unroll
    for (int j = 0; j < 2; ++j) {
      const int dd = dr + 32 * j;
      const unsigned int* row = &tileT[dd * 33 + ch * 4];
      uint4 o; o.x = row[0]; o.y = row[1]; o.z = row[2]; o.w = row[3];
      *(uint4*)(xt + (size_t)(d0 + dd) * K_DIM + n0 + ch * 8) = o;
    }
  }
}

// ---------------- phase 2: Gram GEMM, upper tile-pairs ---------------------
// job bid < 504: p = bid % 21, kz = bid / 21. K split into 512 BK32 stages,
// kz<8 get 22 stages, else 21.
__device__ void phase2(const unsigned short* __restrict__ xt,
                       unsigned short* __restrict__ parts,
                       unsigned char* smem, int bid, int t) {
  unsigned short* ldsA = (unsigned short*)smem;          // 128 x 32
  unsigned short* ldsB = ldsA + 4096;

  const int p  = bid % NPAIR;
  const int kz = bid / NPAIR;
  const int mi = MI_TAB[p];
  const int ni = NI_TAB[p];
  const int m0 = mi * 128;
  const int n0 = ni * 128;
  const bool diag = (mi == ni);

  const int wave = t >> 6;
  const int lane = t & 63;
  const int wm   = (wave & 3) * 32;
  const int wn   = (wave >> 2) * 64;
  const int lm   = lane & 15;
  const int quad = lane >> 4;
  const int rrow = t >> 2;          // staging: 128 rows x 64 B, 1 load/thread
  const int sub  = t & 3;

  floatx4 zero = {0.f, 0.f, 0.f, 0.f};
  floatx4 acc[2][4];
#pragma unroll
  for (int a = 0; a < 2; ++a)
#pragma unroll
    for (int b = 0; b < 4; ++b) acc[a][b] = zero;

  const int s0 = 21 * kz + (kz < 8 ? kz : 8);
  const int ns = (kz < 8) ? 22 : 21;
  const unsigned short* ldsBr = diag ? ldsA : ldsB;

  for (int it = 0; it < ns; ++it) {
    const int kb = (s0 + it) * 32;
    load_lds16(xt + (size_t)(m0 + rrow) * K_DIM + kb + sub * 8, &ldsA[t * 8]);
    if (!diag)
      load_lds16(xt + (size_t)(n0 + rrow) * K_DIM + kb + sub * 8, &ldsB[t * 8]);
    __syncthreads();

    short8 af[2], bf[4];
#pragma unroll
    for (int a = 0; a < 2; ++a)
      af[a] = *(const short8*)&ldsA[(wm + a * 16 + lm) * 32 + quad * 8];
#pragma unroll
    for (int b = 0; b < 4; ++b)
      bf[b] = *(const short8*)&ldsBr[(wn + b * 16 + lm) * 32 + quad * 8];
#pragma unroll
    for (int a = 0; a < 2; ++a)
#pragma unroll
      for (int b = 0; b < 4; ++b)
        acc[a][b] = __builtin_amdgcn_mfma_f32_16x16x32_bf16(
            af[a], bf[b], acc[a][b], 0, 0, 0);
    __syncthreads();
  }

  // bf16 partial, local 128x128 row-major
  unsigned short* pb = parts + ((size_t)kz * NPAIR + p) * 16384;
#pragma unroll
  for (int a = 0; a < 2; ++a)
#pragma unroll
    for (int b = 0; b < 4; ++b)
#pragma unroll
      for (int r2 = 0; r2 < 4; ++r2) {
        const int lr = wm + a * 16 + quad * 4 + r2;
        const int lc = wn + b * 16 + lm;
        pb[lr * 128 + lc] = (unsigned short)f2bf_u(acc[a][b][r2]);
      }
}

// ---------------- phase 3: reduce + affine + fused mirror ------------------
// 336 half-block units: u = (p, band of 8 rows). Blocks 0..167 fully active.
__device__ void phase3(const unsigned short* __restrict__ parts,
                       float* __restrict__ out,
                       unsigned char* smem, int bid, int t) {
  const int h  = t >> 8;
  const int tt = t & 255;
  const int u  = bid * 2 + h;
  if (u >= NPAIR * 16) return;
  const int p    = u >> 4;
  const int band = u & 15;
  const int mi = MI_TAB[p], ni = NI_TAB[p];
  const int r0 = band * 8;
  const int lrow = tt >> 5;         // 0..7
  const int cb   = (tt & 31) * 4;   // col base

  float s[4] = {0.f, 0.f, 0.f, 0.f};
#pragma unroll
  for (int kz = 0; kz < KSPLIT; ++kz) {
    const unsigned short* pp =
        parts + ((size_t)kz * NPAIR + p) * 16384 + (r0 + lrow) * 128 + cb;
    const uint2 w = *(const uint2*)pp;
    s[0] += __uint_as_float(w.x << 16);
    s[1] += __uint_as_float(w.x & 0xffff0000u);
    s[2] += __uint_as_float(w.y << 16);
    s[3] += __uint_as_float(w.y & 0xffff0000u);
  }
  const float scale = 0.5f / (float)K_DIM;
  float v[4];
#pragma unroll
  for (int i = 0; i < 4; ++i) v[i] = fmaf(s[i], scale, -0.5f);

  float* o = out + (size_t)(mi * 128 + r0 + lrow) * D_DIM + ni * 128 + cb;
  *(float4*)o = make_float4(v[0], v[1], v[2], v[3]);

  float* lt = (float*)smem + h * 1032;     // [8][129]
  if (mi != ni) {
#pragma unroll
    for (int i = 0; i < 4; ++i) lt[lrow * 129 + cb + i] = v[i];
  }
  __syncthreads();
  if (mi != ni) {
    const int ct = tt & 127;               // dest row
    const int hh = tt >> 7;                // dest col group of 4
    float w0 = lt[(hh * 4 + 0) * 129 + ct];
    float w1 = lt[(hh * 4 + 1) * 129 + ct];
    float w2 = lt[(hh * 4 + 2) * 129 + ct];
    float w3 = lt[(hh * 4 + 3) * 129 + ct];
    float* od = out + (size_t)(ni * 128 + ct) * D_DIM + mi * 128 + r0 + hh * 4;
    *(float4*)od = make_float4(w0, w1, w2, w3);
  }
}

// ---------------- fused cooperative kernel ---------------------------------
__global__ __launch_bounds__(512, 4) void fused_kernel(
    const float* __restrict__ x, unsigned short* __restrict__ xt,
    unsigned short* __restrict__ parts, float* __restrict__ out) {
  __shared__ __align__(16) unsigned char smem[SMEM_BYTES];
  cg::grid_group g = cg::this_grid();
  phase1(x, xt, smem, blockIdx.x, threadIdx.x);
  g.sync();
  if (blockIdx.x < NPAIR * KSPLIT)
    phase2(xt, parts, smem, blockIdx.x, threadIdx.x);
  g.sync();
  phase3(parts, out, smem, blockIdx.x, threadIdx.x);
}

// ---------------- non-coop fallback wrappers -------------------------------
__global__ __launch_bounds__(512) void p1_kernel(
    const float* __restrict__ x, unsigned short* __restrict__ xt) {
  __shared__ __align__(16) unsigned char smem[SMEM_BYTES];
  phase1(x, xt, smem, blockIdx.x, threadIdx.x);
}
__global__ __launch_bounds__(512, 4) void p2_kernel(
    const unsigned short* __restrict__ xt, unsigned short* __restrict__ parts) {
  __shared__ __align__(16) unsigned char smem[SMEM_BYTES];
  phase2(xt, parts, smem, blockIdx.x, threadIdx.x);
}
__global__ __launch_bounds__(512) void p3_kernel(
    const unsigned short* __restrict__ parts, float* __restrict__ out) {
  __shared__ __align__(16) unsigned char smem[SMEM_BYTES];
  phase3(parts, out, smem, blockIdx.x, threadIdx.x);
}

extern "C" void kernel_launch(void* const* d_in, const int* in_sizes, int n_in,
                              void* d_out, int out_size, void* d_ws, size_t ws_size,
                              hipStream_t stream) {
  const float* x = (const float*)d_in[0];           // [16384,768] f32
  float* out = (float*)d_out;                       // [768,768] f32
  unsigned short* xt = (unsigned short*)d_ws;       // bf16 [768][16384]
  unsigned short* parts = (unsigned short*)((char*)d_ws + XT_BYTES);

  void* args[] = {(void*)&x, (void*)&xt, (void*)&parts, (void*)&out};
  hipError_t e = hipLaunchCooperativeKernel(
      reinterpret_cast<void*>(fused_kernel), dim3(NBLK), dim3(512),
      args, 0, stream);
  if (e != hipSuccess) {
    // capture-safe fallback: same phases as plain kernels
    p1_kernel<<<NBLK, 512, 0, stream>>>(x, xt);
    p2_kernel<<<NPAIR * KSPLIT, 512, 0, stream>>>(xt, parts);
    p3_kernel<<<168, 512, 0, stream>>>(parts, out);
  }
}

// Round 8
// 262.362 us; speedup vs baseline: 1.0206x; 1.0206x over previous
//
#include <hip/hip_runtime.h>
#include <hip/hip_bf16.h>

// DecorrelationGradient, KAPPA = 0.5:
//   out = 0.5 * (X^T X / N) - 0.5   (diag terms cancel exactly at k=0.5)
// X [16384, 768] fp32.
//
// R7b: compile fix only (float4 array init via make_float4, not ext-vector).
// Structure: stream-ordered 2 dispatches; split-K fixup fuses reduce+mirror
// into the GEMM (last block per tile-pair, agent-scope acq_rel counter).
// K1: transpose+cast X -> XT [768,16384] bf16 (+ zero 21 counters)
// K2: MFMA GEMM (upper pairs, 128x128, BK=32, KSPLIT=24) + fixup reduce

#define D_DIM    768
#define K_DIM    16384
#define NPAIR    21
#define KSPLIT   24
#define XT_BYTES   ((size_t)D_DIM * K_DIM * 2)                 // 24 MiB
#define PART_BYTES ((size_t)KSPLIT * NPAIR * 16384 * 4)        // 33 MiB f32
#define CNT_OFF    (XT_BYTES + PART_BYTES)

__device__ __constant__ int MI_TAB[NPAIR] = {0,0,0,0,0,0, 1,1,1,1,1, 2,2,2,2, 3,3,3, 4,4, 5};
__device__ __constant__ int NI_TAB[NPAIR] = {0,1,2,3,4,5, 1,2,3,4,5, 2,3,4,5, 3,4,5, 4,5, 5};

typedef __attribute__((ext_vector_type(8))) short short8;     // bf16 A/B frag
typedef __attribute__((ext_vector_type(4))) float floatx4;    // fp32 C/D frag

typedef __attribute__((address_space(3))) unsigned short lds_ushort;
typedef __attribute__((address_space(1))) const unsigned short g_ushort;

__device__ __forceinline__ void load_lds16(const unsigned short* g, unsigned short* l) {
  __builtin_amdgcn_global_load_lds((g_ushort*)g, (lds_ushort*)l, 16, 0, 0);
}

__device__ __forceinline__ unsigned int f2bf_u(float f) {     // RNE, as uint
  unsigned int u = __float_as_uint(f);
  u += 0x7fffu + ((u >> 16) & 1u);
  return u >> 16;
}

// ---------------- K1: transpose + cast (+ counter zero) --------------------
__global__ __launch_bounds__(256) void transpose_cast_kernel(
    const float* __restrict__ x, unsigned short* __restrict__ xt,
    unsigned int* __restrict__ counters) {
  __shared__ __align__(16) unsigned int tileT[64 * 33];   // [d][npair]
  if (blockIdx.x == 0 && blockIdx.y == 0 && threadIdx.x < NPAIR)
    counters[threadIdx.x * 16] = 0;      // one counter per 64B line
  const int d0 = blockIdx.x * 64;
  const int n0 = blockIdx.y * 64;
  const int t  = threadIdx.x;
  const int f4 = t & 15;
  const int np = t >> 4;
#pragma unroll
  for (int j = 0; j < 2; ++j) {
    const int npg = np + 16 * j;
    const float* p0 = x + (size_t)(n0 + 2 * npg) * D_DIM + d0 + 4 * f4;
    float4 v0 = *(const float4*)p0;
    float4 v1 = *(const float4*)(p0 + D_DIM);
    tileT[(4 * f4 + 0) * 33 + npg] = f2bf_u(v0.x) | (f2bf_u(v1.x) << 16);
    tileT[(4 * f4 + 1) * 33 + npg] = f2bf_u(v0.y) | (f2bf_u(v1.y) << 16);
    tileT[(4 * f4 + 2) * 33 + npg] = f2bf_u(v0.z) | (f2bf_u(v1.z) << 16);
    tileT[(4 * f4 + 3) * 33 + npg] = f2bf_u(v0.w) | (f2bf_u(v1.w) << 16);
  }
  __syncthreads();
  const int ch = t & 7;
  const int dr = t >> 3;
#pragma unroll
  for (int j = 0; j < 2; ++j) {
    const int dd = dr + 32 * j;
    const unsigned int* row = &tileT[dd * 33 + ch * 4];
    uint4 o; o.x = row[0]; o.y = row[1]; o.z = row[2]; o.w = row[3];
    *(uint4*)(xt + (size_t)(d0 + dd) * K_DIM + n0 + ch * 8) = o;
  }
}

// ---------------- K2: Gram GEMM + split-K fixup ----------------------------
// grid (NPAIR, KSPLIT), 512 threads. 512 BK32 stages split: kz<8 -> 22, else 21.
__global__ __launch_bounds__(512, 4) void gram_gemm_fix_kernel(
    const unsigned short* __restrict__ xt,
    float* __restrict__ parts,               // f32 [KSPLIT][NPAIR][16384]
    unsigned int* __restrict__ counters,
    float* __restrict__ out) {
  __shared__ __align__(16) unsigned char smem[16384];     // ldsA/B, then lt
  __shared__ int s_last;
  unsigned short* ldsA = (unsigned short*)smem;           // 128 x 32 bf16
  unsigned short* ldsB = ldsA + 4096;

  const int p  = blockIdx.x;
  const int kz = blockIdx.y;
  const int mi = MI_TAB[p];
  const int ni = NI_TAB[p];
  const int m0 = mi * 128;
  const int n0 = ni * 128;
  const bool diag = (mi == ni);

  const int t    = threadIdx.x;
  const int wave = t >> 6;
  const int lane = t & 63;
  const int wm   = (wave & 3) * 32;
  const int wn   = (wave >> 2) * 64;
  const int lm   = lane & 15;
  const int quad = lane >> 4;
  const int rrow = t >> 2;          // staging: 128 rows x 64 B, 1 load/thread
  const int sub  = t & 3;

  floatx4 zero = {0.f, 0.f, 0.f, 0.f};
  floatx4 acc[2][4];
#pragma unroll
  for (int a = 0; a < 2; ++a)
#pragma unroll
    for (int b = 0; b < 4; ++b) acc[a][b] = zero;

  const int s0 = 21 * kz + (kz < 8 ? kz : 8);
  const int ns = (kz < 8) ? 22 : 21;
  const unsigned short* ldsBr = diag ? ldsA : ldsB;

  for (int it = 0; it < ns; ++it) {
    const int kb = (s0 + it) * 32;
    load_lds16(xt + (size_t)(m0 + rrow) * K_DIM + kb + sub * 8, &ldsA[t * 8]);
    if (!diag)
      load_lds16(xt + (size_t)(n0 + rrow) * K_DIM + kb + sub * 8, &ldsB[t * 8]);
    __syncthreads();

    short8 af[2], bf[4];
#pragma unroll
    for (int a = 0; a < 2; ++a)
      af[a] = *(const short8*)&ldsA[(wm + a * 16 + lm) * 32 + quad * 8];
#pragma unroll
    for (int b = 0; b < 4; ++b)
      bf[b] = *(const short8*)&ldsBr[(wn + b * 16 + lm) * 32 + quad * 8];
#pragma unroll
    for (int a = 0; a < 2; ++a)
#pragma unroll
      for (int b = 0; b < 4; ++b)
        acc[a][b] = __builtin_amdgcn_mfma_f32_16x16x32_bf16(
            af[a], bf[b], acc[a][b], 0, 0, 0);
    __syncthreads();
  }

  // f32 partial, local 128x128 row-major; quarter-wave rows -> 64 B segments
  float* pb = parts + ((size_t)kz * NPAIR + p) * 16384;
#pragma unroll
  for (int a = 0; a < 2; ++a)
#pragma unroll
    for (int b = 0; b < 4; ++b)
#pragma unroll
      for (int r2 = 0; r2 < 4; ++r2) {
        const int lr = wm + a * 16 + quad * 4 + r2;
        const int lc = wn + b * 16 + lm;
        pb[lr * 128 + lc] = acc[a][b][r2];
      }

  // ---- fixup: last block per pair reduces ----
  __syncthreads();                       // all waves' stores drained (vmcnt(0) before barrier)
  if (t == 0) {
    __threadfence();                     // agent release: flush partial stores
    unsigned int old = __hip_atomic_fetch_add(&counters[p * 16], 1u,
                                              __ATOMIC_ACQ_REL,
                                              __HIP_MEMORY_SCOPE_AGENT);
    s_last = (old == KSPLIT - 1);
  }
  __syncthreads();
  if (!s_last) return;
  __threadfence();                       // acquire side

  // reduce 24 partials: thread t -> row = t>>2, cols (t&3)*32 .. +32
  const int row = t >> 2;
  const int cs  = (t & 3) * 32;
  float4 s[8];
#pragma unroll
  for (int i = 0; i < 8; ++i) s[i] = make_float4(0.f, 0.f, 0.f, 0.f);
  for (int k = 0; k < KSPLIT; ++k) {
    const float* pp = parts + ((size_t)k * NPAIR + p) * 16384 + row * 128 + cs;
#pragma unroll
    for (int i = 0; i < 8; ++i) {
      const float4 v = *(const float4*)(pp + 4 * i);
      s[i].x += v.x; s[i].y += v.y; s[i].z += v.z; s[i].w += v.w;
    }
  }
  const float scale = 0.5f / (float)K_DIM;
  float4 v[8];
#pragma unroll
  for (int i = 0; i < 8; ++i) {
    v[i].x = fmaf(s[i].x, scale, -0.5f);
    v[i].y = fmaf(s[i].y, scale, -0.5f);
    v[i].z = fmaf(s[i].z, scale, -0.5f);
    v[i].w = fmaf(s[i].w, scale, -0.5f);
  }
  // upper tile write (coalesced)
  float* o = out + (size_t)(m0 + row) * D_DIM + n0 + cs;
#pragma unroll
  for (int i = 0; i < 8; ++i) *(float4*)(o + 4 * i) = v[i];

  if (diag) return;

  // mirror via LDS-transposed 16-row chunks (stride 132 floats, 16B-aligned)
  float* lt = (float*)smem;              // 16 x 132 = 8448 B (fits smem)
  for (int chn = 0; chn < 8; ++chn) {
    __syncthreads();
    if ((row >> 4) == chn) {
      const int r16 = row & 15;
#pragma unroll
      for (int i = 0; i < 8; ++i)
        *(float4*)&lt[r16 * 132 + cs + 4 * i] = v[i];
    }
    __syncthreads();
    const int dr = t >> 2;               // dest row = source col
    const int q  = t & 3;                // dest col group of 4
    float w0 = lt[(q * 4 + 0) * 132 + dr];
    float w1 = lt[(q * 4 + 1) * 132 + dr];
    float w2 = lt[(q * 4 + 2) * 132 + dr];
    float w3 = lt[(q * 4 + 3) * 132 + dr];
    float* od = out + (size_t)(n0 + dr) * D_DIM + m0 + chn * 16 + q * 4;
    *(float4*)od = make_float4(w0, w1, w2, w3);
  }
}

// ---------------- fallback (small ws): atomic path -------------------------
__global__ __launch_bounds__(256) void init_out_kernel(float* __restrict__ out) {
  size_t i = (size_t)blockIdx.x * 256 + threadIdx.x;
  ((float4*)out)[i] = make_float4(-0.5f, -0.5f, -0.5f, -0.5f);
}
__global__ __launch_bounds__(256, 4) void gram_gemm_atomic_kernel(
    const unsigned short* __restrict__ xt, float* __restrict__ out) {
  __shared__ __align__(16) unsigned short ldsA[128 * 32];
  __shared__ __align__(16) unsigned short ldsB[128 * 32];
  const int p  = blockIdx.x;
  const int mi = MI_TAB[p];
  const int ni = NI_TAB[p];
  const int m0 = mi * 128, n0 = ni * 128;
  const int kz = blockIdx.y;
  const int t = threadIdx.x, wave = t >> 6, lane = t & 63;
  const int wm = (wave >> 1) * 64, wn = (wave & 1) * 64;
  const int lm = lane & 15, quad = lane >> 4;
  floatx4 zero = {0.f, 0.f, 0.f, 0.f};
  floatx4 acc[4][4];
#pragma unroll
  for (int a = 0; a < 4; ++a)
#pragma unroll
    for (int b = 0; b < 4; ++b) acc[a][b] = zero;
  const int kbeg = kz * (K_DIM / 8);
  for (int it = 0; it < (K_DIM / 8) / 32; ++it) {
    const int kb = kbeg + it * 32;
#pragma unroll
    for (int i = 0; i < 2; ++i) {
      const int flatL = (wave * 2 + i) * 64 + lane;
      const int rr = flatL >> 2, sb = flatL & 3;
      load_lds16(xt + (size_t)(m0 + rr) * K_DIM + kb + sb * 8, &ldsA[flatL * 8]);
      load_lds16(xt + (size_t)(n0 + rr) * K_DIM + kb + sb * 8, &ldsB[flatL * 8]);
    }
    __syncthreads();
    short8 af[4], bf[4];
#pragma unroll
    for (int a = 0; a < 4; ++a)
      af[a] = *(const short8*)&ldsA[(wm + a * 16 + lm) * 32 + quad * 8];
#pragma unroll
    for (int b = 0; b < 4; ++b)
      bf[b] = *(const short8*)&ldsB[(wn + b * 16 + lm) * 32 + quad * 8];
#pragma unroll
    for (int a = 0; a < 4; ++a)
#pragma unroll
      for (int b = 0; b < 4; ++b)
        acc[a][b] = __builtin_amdgcn_mfma_f32_16x16x32_bf16(af[a], bf[b], acc[a][b], 0, 0, 0);
    __syncthreads();
  }
  const float scale = 0.5f / (float)K_DIM;
#pragma unroll
  for (int a = 0; a < 4; ++a)
#pragma unroll
    for (int b = 0; b < 4; ++b)
#pragma unroll
      for (int r2 = 0; r2 < 4; ++r2) {
        const int gr = m0 + wm + a * 16 + quad * 4 + r2;
        const int gc = n0 + wn + b * 16 + lm;
        atomicAdd(&out[(size_t)gr * D_DIM + gc], acc[a][b][r2] * scale);
        if (mi != ni)
          atomicAdd(&out[(size_t)gc * D_DIM + gr], acc[a][b][r2] * scale);
      }
}

extern "C" void kernel_launch(void* const* d_in, const int* in_sizes, int n_in,
                              void* d_out, int out_size, void* d_ws, size_t ws_size,
                              hipStream_t stream) {
  const float* x = (const float*)d_in[0];           // [16384,768] f32
  float* out = (float*)d_out;                       // [768,768] f32
  unsigned short* xt = (unsigned short*)d_ws;       // bf16 [768][16384]

  if (ws_size >= CNT_OFF + NPAIR * 64) {
    float* parts = (float*)((char*)d_ws + XT_BYTES);
    unsigned int* counters = (unsigned int*)((char*)d_ws + CNT_OFF);
    transpose_cast_kernel<<<dim3(12, 256), 256, 0, stream>>>(x, xt, counters);
    gram_gemm_fix_kernel<<<dim3(NPAIR, KSPLIT), 512, 0, stream>>>(xt, parts, counters, out);
  } else {
    transpose_cast_kernel<<<dim3(12, 256), 256, 0, stream>>>(x, xt, nullptr);
    init_out_kernel<<<576, 256, 0, stream>>>(out);
    gram_gemm_atomic_kernel<<<dim3(NPAIR, 8), 256, 0, stream>>>(xt, out);
  }
}